// Round 19
// baseline (77.276 us; speedup 1.0000x reference)
//
#include <hip/hip_runtime.h>
#include <hip/hip_bf16.h>

using short8 = __attribute__((ext_vector_type(8))) short;
using sh4    = __attribute__((ext_vector_type(4))) short;
using f32x4  = __attribute__((ext_vector_type(4))) float;
typedef unsigned short ushort_t;
typedef unsigned long long u64;

constexpr int BB = 2, FF = 8, CIN = 16, COUT = 32, HH = 128, WW = 128;
constexpr int HW   = HH * WW;          // 16384
constexpr int NIMG = BB * FF;          // 16
constexpr int TIL = 16, HALO = 2, LP = 20, NPX = 400;
constexpr int PW  = 132;               // padded pixel-major dim for t1p (2-px ring)
constexpr int NRING = PW * PW - HH * WW;   // 1040 ring px per img
constexpr int WFN = 17 * 2 * 512;      // 17408 ushorts per conv (A-frags)
constexpr int NCPY = 64;               // BN accumulator copies
constexpr float FXS  = 65536.f;
constexpr float IFXS = 1.f / 65536.f;

__device__ const int DOFF[17] = { -42,-41,-40,-39,-38, -18,2,22, 38,39,40,41,42, -22,-2,18, 0 };
// D2[n] = (dx*PW + dy) * 32 : tap offsets in t1p ushort units
__device__ const int D2[17] = { -8512,-8480,-8448,-8416,-8384, -4160,64,4288,
                                 8384,8416,8448,8480,8512, -4288,-64,4160, 0 };

__device__ __forceinline__ float leaky(float v) { return fmaxf(v, 0.01f * v); }
__device__ __forceinline__ ushort_t f2bf(float f) {
    return __builtin_bit_cast(ushort_t, __float2bfloat16(f));
}
__device__ __forceinline__ float bf2f(ushort_t h) {
    unsigned u = ((unsigned)h) << 16;
    return __builtin_bit_cast(float, u);
}

// acc layout: [NCPY][64] u64 (per copy: sum[32], sq[32])
__device__ __forceinline__ void prm_from_acc(const u64* __restrict__ acc,
                                             const float* __restrict__ gamma,
                                             const float* __restrict__ beta,
                                             float* sprm, int tid)
{
    if (tid < COUT) {
        long long ls = 0, lq = 0;
#pragma unroll
        for (int k = 0; k < NCPY; ++k) {
            ls += (long long)acc[k * 64 + tid];
            lq += (long long)acc[k * 64 + COUT + tid];
        }
        float s = (float)ls * IFXS;
        float q = (float)lq * IFXS;
        const float n = (float)(NIMG * HW);
        float mu  = s / n;
        float var = q / n - mu * mu;
        float a   = gamma[tid] * rsqrtf(var + 1e-5f);
        sprm[tid]        = a;
        sprm[COUT + tid] = beta[tid] - mu * a;
    }
    __syncthreads();
}

// ---- dispatch 1: weight prep + zero BN accumulators + zero t1p halo ring ----
__global__ __launch_bounds__(256)
void prep_weights(const float* __restrict__ W1, const float* __restrict__ W2,
                  ushort_t* __restrict__ Wf1, ushort_t* __restrict__ Wf2,
                  u64* __restrict__ accz, ushort_t* __restrict__ t1p)
{
    int idx = blockIdx.x * 256 + threadIdx.x;
    if (blockIdx.y == 0) {
        if (blockIdx.x < (2 * NCPY * 64) / 256) accz[idx] = 0ull;
        if (idx < NIMG * NRING) {                      // zero 2-px ring of t1p
            int img = idx / NRING, r = idx - img * NRING;
            int row, col;
            if (r < 528) { int rr = r / 132; row = rr < 2 ? rr : rr + 128; col = r % 132; }
            else { int q = r - 528; row = 2 + (q >> 2); int c4 = q & 3; col = c4 < 2 ? c4 : c4 + 128; }
            f32x4* dst = (f32x4*)(t1p + ((size_t)(img * PW + row) * PW + col) * 32);
            f32x4 z = {0.f, 0.f, 0.f, 0.f};
            dst[0] = z; dst[1] = z; dst[2] = z; dst[3] = z;
        }
    }
    int which = blockIdx.y;
    const float* W = which ? W2 : W1;
    ushort_t* Wf   = which ? Wf2 : Wf1;
    int ci         = which ? COUT : CIN;
    int j  = idx & 7;
    int l  = (idx >> 3) & 63;
    int oh = (idx >> 9) & 1;
    int n  = idx >> 10;
    int oc = oh * 16 + (l & 15);
    int k  = ((l >> 4) << 3) + j;
    int c  = which ? k : (k & 15);
    const float* wp = W + ((size_t)oc * ci + c) * 16;
    float v;
    if (n < 16) v = -wp[n];
    else { v = 0.f; for (int q = 0; q < 16; ++q) v += wp[q]; }
    Wf[idx] = f2bf(v);
}

// ---- dispatch 2: conv1 (LDS-staged, round-15 structure, unchanged) ----
__global__ __launch_bounds__(256)
void conv1_k(const float* __restrict__ inf, const ushort_t* __restrict__ Wf,
             const float* __restrict__ bk, ushort_t* __restrict__ tout,
             u64* __restrict__ acc_g)
{
    __shared__ __align__(16) ushort_t lds[NPX * 32];
    __shared__ float redS[4][COUT], redQ[4][COUT];
    const int tid = threadIdx.x, tileid = blockIdx.x, img = blockIdx.y;
    const int tx   = (tileid & 7) * TIL;
    const int ty   = (tileid >> 3) * TIL;
    const int lane = tid & 63;
    const int wid  = tid >> 6;
    const int rxl  = lane & 15;
    const int cq   = lane >> 4;

#pragma unroll
    for (int e = 0; e < 4; ++e) {
        int task = e * 256 + tid;
        if (task < 800) {
            int h  = task >= 400 ? 1 : 0;
            int p  = task - h * 400;
            int ry = p / LP, rx = p - ry * LP;
            int gh = ty + ry - HALO, gw = tx + rx - HALO;
            bool ok = (unsigned)gh < (unsigned)HH && (unsigned)gw < (unsigned)WW;
            int ghc = min(max(gh, 0), HH - 1), gwc = min(max(gw, 0), WW - 1);
            const float* base = inf + (((size_t)(img >> 3) * CIN + 8 * h) * FF + (img & 7)) * HW
                                   + ghc * WW + gwc;
            short8 hi8, lo8;
#pragma unroll
            for (int cc = 0; cc < 8; ++cc) {
                float v = base[(size_t)cc * FF * HW];
                v = ok ? v : 0.f;
                ushort_t hi = f2bf(v);
                hi8[cc] = (short)hi;
                lo8[cc] = (short)f2bf(v - bf2f(hi));
            }
            int swz = (p & 3) ^ ((p >> 2) & 3);
            *(short8*)&lds[p * 32 + 8 * (h ^ swz)]       = hi8;
            *(short8*)&lds[p * 32 + 8 * ((2 + h) ^ swz)] = lo8;
        }
    }
    __syncthreads();

    f32x4 acc[4][2];
#pragma unroll
    for (int ng = 0; ng < 4; ++ng)
#pragma unroll
        for (int oh = 0; oh < 2; ++oh) acc[ng][oh] = f32x4{0.f, 0.f, 0.f, 0.f};

    int q0[4];
#pragma unroll
    for (int ng = 0; ng < 4; ++ng) q0[ng] = (wid * 4 + ng + HALO) * LP + (rxl + HALO);

    const ushort_t* wl = Wf + (size_t)lane * 8;

#pragma unroll
    for (int n = 0; n < 17; ++n) {
        short8 A0 = *(const short8*)(wl + (size_t)(n * 2 + 0) * 512);
        short8 A1 = *(const short8*)(wl + (size_t)(n * 2 + 1) * 512);
        int dof = DOFF[n];
#pragma unroll
        for (int ng = 0; ng < 4; ++ng) {
            int p   = q0[ng] + dof;
            int swz = (p & 3) ^ ((p >> 2) & 3);
            short8 Bv = *(const short8*)&lds[p * 32 + 8 * (cq ^ swz)];
            acc[ng][0] = __builtin_amdgcn_mfma_f32_16x16x32_bf16(A0, Bv, acc[ng][0], 0, 0, 0);
            acc[ng][1] = __builtin_amdgcn_mfma_f32_16x16x32_bf16(A1, Bv, acc[ng][1], 0, 0, 0);
        }
    }

    float ssum[2][4], ssq[2][4];
#pragma unroll
    for (int oh = 0; oh < 2; ++oh)
#pragma unroll
        for (int rr = 0; rr < 4; ++rr) {
            float b = bk[oh * 16 + cq * 4 + rr];
#pragma unroll
            for (int ng = 0; ng < 4; ++ng) acc[ng][oh][rr] += b;
            ssum[oh][rr] = 0.f; ssq[oh][rr] = 0.f;
        }

#pragma unroll
    for (int ng = 0; ng < 4; ++ng) {
        int gh = ty + wid * 4 + ng, gw = tx + rxl;
        size_t pxb = ((size_t)img * HW + gh * WW + gw) * 32;
#pragma unroll
        for (int oh = 0; oh < 2; ++oh) {
            sh4 sv;
#pragma unroll
            for (int rr = 0; rr < 4; ++rr) {
                float v = acc[ng][oh][rr];
                sv[rr] = (short)f2bf(v);
                ssum[oh][rr] += v;
                ssq[oh][rr]   = fmaf(v, v, ssq[oh][rr]);
            }
            *(sh4*)&tout[pxb + oh * 16 + cq * 4] = sv;
        }
    }

#pragma unroll
    for (int oh = 0; oh < 2; ++oh)
#pragma unroll
        for (int rr = 0; rr < 4; ++rr) {
            float s = ssum[oh][rr], q = ssq[oh][rr];
#pragma unroll
            for (int m = 1; m < 16; m <<= 1) { s += __shfl_xor(s, m); q += __shfl_xor(q, m); }
            if (rxl == 0) {
                redS[wid][oh * 16 + cq * 4 + rr] = s;
                redQ[wid][oh * 16 + cq * 4 + rr] = q;
            }
        }
    __syncthreads();

    if (tid < COUT) {
        float s = redS[0][tid] + redS[1][tid] + redS[2][tid] + redS[3][tid];
        float q = redQ[0][tid] + redQ[1][tid] + redQ[2][tid] + redQ[3][tid];
        long long qs = (long long)llrintf(s * FXS);
        long long qq = (long long)llrintf(q * FXS);
        int copy = (img * 64 + tileid) & (NCPY - 1);
        atomicAdd(&acc_g[copy * 64 + tid],        (u64)qs);
        atomicAdd(&acc_g[copy * 64 + COUT + tid], (u64)qq);
    }
}

// ---- dispatch 3: bnapply — t1 -> padded t1p with BN1 affine + leaky applied ----
__global__ __launch_bounds__(256)
void bnapply(const ushort_t* __restrict__ t1, const u64* __restrict__ acc1,
             const float* __restrict__ g1, const float* __restrict__ be1,
             ushort_t* __restrict__ t1p)
{
    __shared__ float sprm[2 * COUT];
    prm_from_acc(acc1, g1, be1, sprm, threadIdx.x);
#pragma unroll
    for (int e = 0; e < 4; ++e) {
        int task = blockIdx.x * 1024 + e * 256 + threadIdx.x;   // < 1048576
        int g   = task & 3;
        int p   = (task >> 2) & (HW - 1);
        int img = task >> 16;
        short8 raw = *(const short8*)(t1 + ((size_t)img * HW + p) * 32 + 8 * g);
        short8 hv;
#pragma unroll
        for (int jj = 0; jj < 8; ++jj) {
            int c = 8 * g + jj;
            float v = bf2f((ushort_t)raw[jj]);
            hv[jj] = (short)f2bf(leaky(fmaf(sprm[c], v, sprm[COUT + c])));
        }
        int row = (p >> 7) + 2, col = (p & 127) + 2;
        *(short8*)(t1p + ((size_t)(img * PW + row) * PW + col) * 32 + 8 * g) = hv;
    }
}

// ---- dispatch 4: conv2 — LDS-free, B-fragments loaded directly from t1p ----
__global__ __launch_bounds__(256)
void conv2_k(const ushort_t* __restrict__ t1p, const ushort_t* __restrict__ Wf,
             const float* __restrict__ bk, ushort_t* __restrict__ tout,
             u64* __restrict__ acc_g)
{
    __shared__ float redS[4][COUT], redQ[4][COUT];
    const int tid = threadIdx.x, tileid = blockIdx.x, img = blockIdx.y;
    const int tx   = (tileid & 7) * TIL;
    const int ty   = (tileid >> 3) * TIL;
    const int lane = tid & 63;
    const int wid  = tid >> 6;
    const int rxl  = lane & 15;
    const int cq   = lane >> 4;

    f32x4 acc[4][2];
#pragma unroll
    for (int ng = 0; ng < 4; ++ng)
#pragma unroll
        for (int oh = 0; oh < 2; ++oh) acc[ng][oh] = f32x4{0.f, 0.f, 0.f, 0.f};

    const ushort_t* bp[4];
#pragma unroll
    for (int ng = 0; ng < 4; ++ng)
        bp[ng] = t1p + ((size_t)(img * PW + ty + wid * 4 + ng + 2) * PW + tx + rxl + 2) * 32 + cq * 8;

    const ushort_t* wl = Wf + (size_t)lane * 8;

#pragma unroll
    for (int n = 0; n < 17; ++n) {
        short8 A0 = *(const short8*)(wl + (size_t)(n * 2 + 0) * 512);
        short8 A1 = *(const short8*)(wl + (size_t)(n * 2 + 1) * 512);
        int d = D2[n];
#pragma unroll
        for (int ng = 0; ng < 4; ++ng) {
            short8 Bv = *(const short8*)(bp[ng] + d);
            acc[ng][0] = __builtin_amdgcn_mfma_f32_16x16x32_bf16(A0, Bv, acc[ng][0], 0, 0, 0);
            acc[ng][1] = __builtin_amdgcn_mfma_f32_16x16x32_bf16(A1, Bv, acc[ng][1], 0, 0, 0);
        }
    }

    float ssum[2][4], ssq[2][4];
#pragma unroll
    for (int oh = 0; oh < 2; ++oh)
#pragma unroll
        for (int rr = 0; rr < 4; ++rr) {
            float b = bk[oh * 16 + cq * 4 + rr];
#pragma unroll
            for (int ng = 0; ng < 4; ++ng) acc[ng][oh][rr] += b;
            ssum[oh][rr] = 0.f; ssq[oh][rr] = 0.f;
        }

#pragma unroll
    for (int ng = 0; ng < 4; ++ng) {
        int gh = ty + wid * 4 + ng, gw = tx + rxl;
        size_t pxb = ((size_t)img * HW + gh * WW + gw) * 32;
#pragma unroll
        for (int oh = 0; oh < 2; ++oh) {
            sh4 sv;
#pragma unroll
            for (int rr = 0; rr < 4; ++rr) {
                float v = acc[ng][oh][rr];
                sv[rr] = (short)f2bf(v);
                ssum[oh][rr] += v;
                ssq[oh][rr]   = fmaf(v, v, ssq[oh][rr]);
            }
            *(sh4*)&tout[pxb + oh * 16 + cq * 4] = sv;
        }
    }

#pragma unroll
    for (int oh = 0; oh < 2; ++oh)
#pragma unroll
        for (int rr = 0; rr < 4; ++rr) {
            float s = ssum[oh][rr], q = ssq[oh][rr];
#pragma unroll
            for (int m = 1; m < 16; m <<= 1) { s += __shfl_xor(s, m); q += __shfl_xor(q, m); }
            if (rxl == 0) {
                redS[wid][oh * 16 + cq * 4 + rr] = s;
                redQ[wid][oh * 16 + cq * 4 + rr] = q;
            }
        }
    __syncthreads();

    if (tid < COUT) {
        float s = redS[0][tid] + redS[1][tid] + redS[2][tid] + redS[3][tid];
        float q = redQ[0][tid] + redQ[1][tid] + redQ[2][tid] + redQ[3][tid];
        long long qs = (long long)llrintf(s * FXS);
        long long qq = (long long)llrintf(q * FXS);
        int copy = (img * 64 + tileid) & (NCPY - 1);
        atomicAdd(&acc_g[copy * 64 + tid],        (u64)qs);
        atomicAdd(&acc_g[copy * 64 + COUT + tid], (u64)qq);
    }
}

// ---- dispatch 5: BN2 affine + leaky + flat-reshape octet mean ----
__global__ __launch_bounds__(256)
void finalize_k(const ushort_t* __restrict__ t2, const u64* __restrict__ acc2,
                const float* __restrict__ g2, const float* __restrict__ be2,
                float* __restrict__ outp)
{
    __shared__ float sprm[2 * COUT];
    prm_from_acc(acc2, g2, be2, sprm, threadIdx.x);
    int base = blockIdx.x * 4096;
#pragma unroll
    for (int e = 0; e < 16; ++e) {
        int gid  = base + e * 256 + threadIdx.x;
        int p    = gid & (HW - 1);
        int rest = gid >> 14;
        int o    = rest & 31;
        int b    = rest >> 5;
        int img  = b * 8 + (o >> 2);
        int cb   = (o & 3) * 8;
        const ushort_t* px = t2 + ((size_t)img * HW + p) * 32 + cb;
        short8 raw = *(const short8*)px;
        float s = 0.f;
#pragma unroll
        for (int j = 0; j < 8; ++j) {
            int c = cb + j;
            float v = bf2f((ushort_t)raw[j]);
            s += leaky(fmaf(sprm[c], v, sprm[COUT + c]));
        }
        outp[gid] = 0.125f * s;
    }
}

extern "C" void kernel_launch(void* const* d_in, const int* in_sizes, int n_in,
                              void* d_out, int out_size, void* d_ws, size_t ws_size,
                              hipStream_t stream)
{
    const float* x   = (const float*)d_in[0];
    const float* W1  = (const float*)d_in[1];
    const float* b1  = (const float*)d_in[2];
    const float* g1  = (const float*)d_in[3];
    const float* be1 = (const float*)d_in[4];
    const float* W2  = (const float*)d_in[5];
    const float* b2  = (const float*)d_in[6];
    const float* g2  = (const float*)d_in[7];
    const float* be2 = (const float*)d_in[8];
    float* out = (float*)d_out;

    const size_t TSZH = (size_t)NIMG * HW * 32;        // 8388608 ush (16 MB)
    const size_t TPSZ = (size_t)NIMG * PW * PW * 32;   // 8921088 ush (17.8 MB)
    ushort_t* t1   = (ushort_t*)d_ws;
    ushort_t* t2   = t1 + TSZH;
    ushort_t* t1p  = t2 + TSZH;
    u64*      acc1 = (u64*)(t1p + TPSZ);               // [NCPY][64] x2 contiguous
    u64*      acc2 = acc1 + NCPY * 64;
    ushort_t* Wf1  = (ushort_t*)(acc2 + NCPY * 64);
    ushort_t* Wf2  = Wf1 + WFN;

    dim3 pg(WFN / 256, 2);
    prep_weights<<<pg, 256, 0, stream>>>(W1, W2, Wf1, Wf2, acc1, t1p);
    dim3 cg_(64, NIMG);
    conv1_k<<<cg_, 256, 0, stream>>>(x, Wf1, b1, t1, acc1);
    bnapply<<<1024, 256, 0, stream>>>(t1, acc1, g1, be1, t1p);
    conv2_k<<<cg_, 256, 0, stream>>>(t1p, Wf2, b2, t2, acc2);
    finalize_k<<<(BB * COUT * HW) / 4096, 256, 0, stream>>>(t2, acc2, g2, be2, out);
}

// Round 20
// 61.297 us; speedup vs baseline: 1.2607x; 1.2607x over previous
//
#include <hip/hip_runtime.h>
#include <hip/hip_bf16.h>

using short8 = __attribute__((ext_vector_type(8))) short;
using sh4    = __attribute__((ext_vector_type(4))) short;
using f32x4  = __attribute__((ext_vector_type(4))) float;
typedef unsigned short ushort_t;
typedef unsigned long long u64;

constexpr int BB = 2, FF = 8, CIN = 16, COUT = 32, HH = 128, WW = 128;
constexpr int HW   = HH * WW;          // 16384
constexpr int NIMG = BB * FF;          // 16
constexpr int TIL = 16, HALO = 2, LP = 20, NPX = 400;
constexpr int WFN = 17 * 2 * 512;      // 17408 ushorts per conv (A-frags)
constexpr int NCPY = 64;               // BN accumulator copies
constexpr float FXS  = 65536.f;
constexpr float IFXS = 1.f / 65536.f;

__device__ const int DOFF[17] = { -42,-41,-40,-39,-38, -18,2,22, 38,39,40,41,42, -22,-2,18, 0 };

__device__ __forceinline__ float leaky(float v) { return fmaxf(v, 0.01f * v); }
__device__ __forceinline__ ushort_t f2bf(float f) {
    return __builtin_bit_cast(ushort_t, __float2bfloat16(f));
}
__device__ __forceinline__ float bf2f(ushort_t h) {
    unsigned u = ((unsigned)h) << 16;
    return __builtin_bit_cast(float, u);
}

// acc layout: [NCPY][64] u64 (per copy: sum[32], sq[32])
__device__ __forceinline__ void prm_from_acc(const u64* __restrict__ acc,
                                             const float* __restrict__ gamma,
                                             const float* __restrict__ beta,
                                             float* sprm, int tid)
{
    if (tid < COUT) {
        long long ls = 0, lq = 0;
#pragma unroll
        for (int k = 0; k < NCPY; ++k) {
            ls += (long long)acc[k * 64 + tid];
            lq += (long long)acc[k * 64 + COUT + tid];
        }
        float s = (float)ls * IFXS;
        float q = (float)lq * IFXS;
        const float n = (float)(NIMG * HW);
        float mu  = s / n;
        float var = q / n - mu * mu;
        float a   = gamma[tid] * rsqrtf(var + 1e-5f);
        sprm[tid]        = a;
        sprm[COUT + tid] = beta[tid] - mu * a;
    }
    __syncthreads();
}

// One conv phase for (img, tile). MODE 0: plane-major fp32 x, K=[xh;xl] vs A=[wh;wh].
// MODE 1: pixel-major bf16 in with BN1 affine+leaky from sprm. Writes bf16 tout;
// accumulates per-channel {sum,sumsq} into spread int64 accumulators (deterministic).
template <int MODE>
__device__ __forceinline__ void conv_phase(
    const float* __restrict__ inf, const ushort_t* __restrict__ inh,
    const ushort_t* __restrict__ Wf, const float* __restrict__ bk,
    const float* sprm, ushort_t* __restrict__ tout, u64* __restrict__ acc_g,
    ushort_t* lds, float (*redS)[COUT], float (*redQ)[COUT],
    int img, int tileid, int tid)
{
    const int tx   = (tileid & 7) * TIL;
    const int ty   = (tileid >> 3) * TIL;
    const int lane = tid & 63;
    const int wid  = tid >> 6;
    const int rxl  = lane & 15;
    const int cq   = lane >> 4;

    if (MODE == 0) {
#pragma unroll
        for (int e = 0; e < 4; ++e) {
            int task = e * 256 + tid;
            if (task < 800) {
                int h  = task >= 400 ? 1 : 0;
                int p  = task - h * 400;
                int ry = p / LP, rx = p - ry * LP;
                int gh = ty + ry - HALO, gw = tx + rx - HALO;
                bool ok = (unsigned)gh < (unsigned)HH && (unsigned)gw < (unsigned)WW;
                int ghc = min(max(gh, 0), HH - 1), gwc = min(max(gw, 0), WW - 1);
                const float* base = inf + (((size_t)(img >> 3) * CIN + 8 * h) * FF + (img & 7)) * HW
                                       + ghc * WW + gwc;
                short8 hi8, lo8;
#pragma unroll
                for (int cc = 0; cc < 8; ++cc) {
                    float v = base[(size_t)cc * FF * HW];
                    v = ok ? v : 0.f;
                    ushort_t hi = f2bf(v);
                    hi8[cc] = (short)hi;
                    lo8[cc] = (short)f2bf(v - bf2f(hi));
                }
                int swz = (p & 3) ^ ((p >> 2) & 3);
                *(short8*)&lds[p * 32 + 8 * (h ^ swz)]       = hi8;
                *(short8*)&lds[p * 32 + 8 * ((2 + h) ^ swz)] = lo8;
            }
        }
    } else {
#pragma unroll
        for (int e = 0; e < 7; ++e) {
            int task = e * 256 + tid;
            if (task < 1600) {
                int g  = task & 3, p = task >> 2;
                int ry = p / LP, rx = p - ry * LP;
                int gh = ty + ry - HALO, gw = tx + rx - HALO;
                bool ok = (unsigned)gh < (unsigned)HH && (unsigned)gw < (unsigned)WW;
                int ghc = min(max(gh, 0), HH - 1), gwc = min(max(gw, 0), WW - 1);
                const ushort_t* px = inh + ((size_t)img * HW + ghc * WW + gwc) * 32 + 8 * g;
                short8 raw = *(const short8*)px;
                short8 hv;
#pragma unroll
                for (int jj = 0; jj < 8; ++jj) {
                    int c = 8 * g + jj;
                    float v = bf2f((ushort_t)raw[jj]);
                    v = leaky(fmaf(sprm[c], v, sprm[COUT + c]));
                    hv[jj] = (short)f2bf(ok ? v : 0.f);
                }
                int swz = (p & 3) ^ ((p >> 2) & 3);
                *(short8*)&lds[p * 32 + 8 * (g ^ swz)] = hv;
            }
        }
    }
    __syncthreads();

    f32x4 acc[4][2];
#pragma unroll
    for (int ng = 0; ng < 4; ++ng)
#pragma unroll
        for (int oh = 0; oh < 2; ++oh) acc[ng][oh] = f32x4{0.f, 0.f, 0.f, 0.f};

    int q0[4];
#pragma unroll
    for (int ng = 0; ng < 4; ++ng) q0[ng] = (wid * 4 + ng + HALO) * LP + (rxl + HALO);

    const ushort_t* wl = Wf + (size_t)lane * 8;

#pragma unroll
    for (int n = 0; n < 17; ++n) {
        short8 A0 = *(const short8*)(wl + (size_t)(n * 2 + 0) * 512);
        short8 A1 = *(const short8*)(wl + (size_t)(n * 2 + 1) * 512);
        int dof = DOFF[n];
#pragma unroll
        for (int ng = 0; ng < 4; ++ng) {
            int p   = q0[ng] + dof;
            int swz = (p & 3) ^ ((p >> 2) & 3);
            short8 Bv = *(const short8*)&lds[p * 32 + 8 * (cq ^ swz)];
            acc[ng][0] = __builtin_amdgcn_mfma_f32_16x16x32_bf16(A0, Bv, acc[ng][0], 0, 0, 0);
            acc[ng][1] = __builtin_amdgcn_mfma_f32_16x16x32_bf16(A1, Bv, acc[ng][1], 0, 0, 0);
        }
    }

    float ssum[2][4], ssq[2][4];
#pragma unroll
    for (int oh = 0; oh < 2; ++oh)
#pragma unroll
        for (int rr = 0; rr < 4; ++rr) {
            float b = bk[oh * 16 + cq * 4 + rr];
#pragma unroll
            for (int ng = 0; ng < 4; ++ng) acc[ng][oh][rr] += b;
            ssum[oh][rr] = 0.f; ssq[oh][rr] = 0.f;
        }

#pragma unroll
    for (int ng = 0; ng < 4; ++ng) {
        int gh = ty + wid * 4 + ng, gw = tx + rxl;
        size_t pxb = ((size_t)img * HW + gh * WW + gw) * 32;
#pragma unroll
        for (int oh = 0; oh < 2; ++oh) {
            sh4 sv;
#pragma unroll
            for (int rr = 0; rr < 4; ++rr) {
                float v = acc[ng][oh][rr];
                sv[rr] = (short)f2bf(v);
                ssum[oh][rr] += v;
                ssq[oh][rr]   = fmaf(v, v, ssq[oh][rr]);
            }
            *(sh4*)&tout[pxb + oh * 16 + cq * 4] = sv;
        }
    }

#pragma unroll
    for (int oh = 0; oh < 2; ++oh)
#pragma unroll
        for (int rr = 0; rr < 4; ++rr) {
            float s = ssum[oh][rr], q = ssq[oh][rr];
#pragma unroll
            for (int m = 1; m < 16; m <<= 1) { s += __shfl_xor(s, m); q += __shfl_xor(q, m); }
            if (rxl == 0) {
                redS[wid][oh * 16 + cq * 4 + rr] = s;
                redQ[wid][oh * 16 + cq * 4 + rr] = q;
            }
        }
    __syncthreads();

    // deterministic BN accumulation: int64 fixed-point atomics, 64-way spread
    if (tid < COUT) {
        float s = redS[0][tid] + redS[1][tid] + redS[2][tid] + redS[3][tid];
        float q = redQ[0][tid] + redQ[1][tid] + redQ[2][tid] + redQ[3][tid];
        long long qs = (long long)llrintf(s * FXS);
        long long qq = (long long)llrintf(q * FXS);
        int copy = (img * 64 + tileid) & (NCPY - 1);
        atomicAdd(&acc_g[copy * 64 + tid],        (u64)qs);
        atomicAdd(&acc_g[copy * 64 + COUT + tid], (u64)qq);
    }
}

// ---- dispatch 1: weight prep (+ zero ALL 2*NCPY*64 = 8192 BN accumulators) ----
__global__ __launch_bounds__(256)
void prep_weights(const float* __restrict__ W1, const float* __restrict__ W2,
                  ushort_t* __restrict__ Wf1, ushort_t* __restrict__ Wf2,
                  u64* __restrict__ accz)
{
    if (blockIdx.y == 0 && blockIdx.x < (2 * NCPY * 64) / 256) {
        accz[blockIdx.x * 256 + threadIdx.x] = 0ull;
    }
    int which = blockIdx.y;
    const float* W = which ? W2 : W1;
    ushort_t* Wf   = which ? Wf2 : Wf1;
    int ci         = which ? COUT : CIN;
    int idx = blockIdx.x * 256 + threadIdx.x;
    int j  = idx & 7;
    int l  = (idx >> 3) & 63;
    int oh = (idx >> 9) & 1;
    int n  = idx >> 10;
    int oc = oh * 16 + (l & 15);
    int k  = ((l >> 4) << 3) + j;
    int c  = which ? k : (k & 15);
    const float* wp = W + ((size_t)oc * ci + c) * 16;
    float v;
    if (n < 16) v = -wp[n];
    else { v = 0.f; for (int q = 0; q < 16; ++q) v += wp[q]; }
    Wf[idx] = f2bf(v);
}

// ---- dispatch 2: conv1 (accumulates BN1 stats, spread atomics) ----
__global__ __launch_bounds__(256)
void conv1_k(const float* __restrict__ x, const ushort_t* __restrict__ Wf1,
             const float* __restrict__ b1, ushort_t* __restrict__ t1,
             u64* __restrict__ acc1)
{
    __shared__ __align__(16) ushort_t lds[NPX * 32];
    __shared__ float redS[4][COUT], redQ[4][COUT];
    conv_phase<0>(x, nullptr, Wf1, b1, nullptr, t1, acc1,
                  lds, redS, redQ, blockIdx.y, blockIdx.x, threadIdx.x);
}

// ---- dispatch 3: conv2 (rebuilds prm1 in head; accumulates BN2 stats) ----
__global__ __launch_bounds__(256)
void conv2_k(const ushort_t* __restrict__ t1, const ushort_t* __restrict__ Wf2,
             const float* __restrict__ b2, const u64* __restrict__ acc1,
             const float* __restrict__ g1, const float* __restrict__ be1,
             ushort_t* __restrict__ t2, u64* __restrict__ acc2)
{
    __shared__ __align__(16) ushort_t lds[NPX * 32];
    __shared__ float redS[4][COUT], redQ[4][COUT];
    __shared__ float sprm[2 * COUT];
    prm_from_acc(acc1, g1, be1, sprm, threadIdx.x);
    conv_phase<1>(nullptr, t1, Wf2, b2, sprm, t2, acc2,
                  lds, redS, redQ, blockIdx.y, blockIdx.x, threadIdx.x);
}

// ---- dispatch 4: BN2 affine + leaky + flat-reshape octet mean ----
__global__ __launch_bounds__(256)
void finalize_k(const ushort_t* __restrict__ t2, const u64* __restrict__ acc2,
                const float* __restrict__ g2, const float* __restrict__ be2,
                float* __restrict__ outp)
{
    __shared__ float sprm[2 * COUT];
    prm_from_acc(acc2, g2, be2, sprm, threadIdx.x);
    int base = blockIdx.x * 4096;
#pragma unroll
    for (int e = 0; e < 16; ++e) {
        int gid  = base + e * 256 + threadIdx.x;
        int p    = gid & (HW - 1);
        int rest = gid >> 14;
        int o    = rest & 31;
        int b    = rest >> 5;
        int img  = b * 8 + (o >> 2);
        int cb   = (o & 3) * 8;
        const ushort_t* px = t2 + ((size_t)img * HW + p) * 32 + cb;
        short8 raw = *(const short8*)px;
        float s = 0.f;
#pragma unroll
        for (int j = 0; j < 8; ++j) {
            int c = cb + j;
            float v = bf2f((ushort_t)raw[j]);
            s += leaky(fmaf(sprm[c], v, sprm[COUT + c]));
        }
        outp[gid] = 0.125f * s;
    }
}

extern "C" void kernel_launch(void* const* d_in, const int* in_sizes, int n_in,
                              void* d_out, int out_size, void* d_ws, size_t ws_size,
                              hipStream_t stream)
{
    const float* x   = (const float*)d_in[0];
    const float* W1  = (const float*)d_in[1];
    const float* b1  = (const float*)d_in[2];
    const float* g1  = (const float*)d_in[3];
    const float* be1 = (const float*)d_in[4];
    const float* W2  = (const float*)d_in[5];
    const float* b2  = (const float*)d_in[6];
    const float* g2  = (const float*)d_in[7];
    const float* be2 = (const float*)d_in[8];
    float* out = (float*)d_out;

    const size_t TSZH = (size_t)NIMG * HW * 32;    // 8388608 bf16 elems (16 MB)
    ushort_t* t1   = (ushort_t*)d_ws;
    ushort_t* t2   = t1 + TSZH;
    u64*      acc1 = (u64*)(t2 + TSZH);            // [NCPY][64]
    u64*      acc2 = acc1 + NCPY * 64;
    ushort_t* Wf1  = (ushort_t*)(acc2 + NCPY * 64);
    ushort_t* Wf2  = Wf1 + WFN;

    dim3 pg(WFN / 256, 2);
    prep_weights<<<pg, 256, 0, stream>>>(W1, W2, Wf1, Wf2, acc1);
    dim3 cg_(64, NIMG);
    conv1_k<<<cg_, 256, 0, stream>>>(x, Wf1, b1, t1, acc1);
    conv2_k<<<cg_, 256, 0, stream>>>(t1, Wf2, b2, acc1, g1, be1, t2, acc2);
    finalize_k<<<(BB * COUT * HW) / 4096, 256, 0, stream>>>(t2, acc2, g2, be2, out);
}